// Round 11
// baseline (216.018 us; speedup 1.0000x reference)
//
#include <hip/hip_runtime.h>
#include <math.h>

// Interaction Network — LDS-free MFMA edge kernels (ILP x2) + LDS-binned aggregation
// with 16-edge-deep MLP scan.
//  K0 nodef (nodes): pack x -> f16x4 {x0,x1,x2,0}
//  K1 msg   (edges): emsg = MLP_R1([x[dst],x[src],ea]), mfma_32x32x16_f16
//  K2 bin   (B x NW blocks): LDS f32 bins; scan edge chunk (4x int4 loads in
//           flight = 16 edges/thread/iter); flush partials
//  K3 red   (nodes): aggr[n] = sum_w partial[b][w][n]
//  K4 node  (nodes): xt = MLP_O([x, aggr]) -> packed f16x4
//  K5 out   (edges): out = sigmoid(MLP_R2([xt[dst],xt[src],emsg]))
// Layer-1 K layout: k0-2 xd | 3 pad | 4-6 xs | 7 pad | 8-11 ea/msg | 12 bias | 13-15 pad
// C layout (HW-verified): col=lane&31, row=(reg&3)+8*(reg>>2)+4*(lane>>5).

typedef __fp16 hf8 __attribute__((ext_vector_type(8)));
typedef _Float16 f16x2 __attribute__((ext_vector_type(2)));
typedef float f32x16 __attribute__((ext_vector_type(16)));
typedef unsigned u32x4 __attribute__((ext_vector_type(4)));

#define NEPC  64   // edges per wave-chunk (two MFMA column tiles X/Y)
#define BS    4096 // nodes per aggregation bin

__device__ __forceinline__ f32x16 mfma16(hf8 a, hf8 b, f32x16 c) {
    return __builtin_amdgcn_mfma_f32_32x32x16_f16(a, b, c, 0, 0, 0);
}
__device__ __forceinline__ unsigned pk2(float a, float b) {
    return __builtin_bit_cast(unsigned, __builtin_amdgcn_cvt_pkrtz(a, b));
}
__device__ __forceinline__ unsigned pk2_relu(float a, float b) {
    return __builtin_bit_cast(unsigned,
        __builtin_amdgcn_cvt_pkrtz(fmaxf(a, 0.f), fmaxf(b, 0.f)));
}
__device__ __forceinline__ unsigned pswap(unsigned v) {
    return (unsigned)__shfl_xor((int)v, 32, 64);   // partner lane = lane ^ 32
}
__device__ __forceinline__ hf8 frag_from(unsigned a, unsigned b, unsigned c, unsigned d) {
    u32x4 v = {a, b, c, d};
    return __builtin_bit_cast(hf8, v);
}

// Build the 3 B-fragments (K=48: ch0..39 + bias@40) from C-layout accumulators
// t0 (ch 0..31) and t1 (ch 32..39), relu applied.
__device__ __forceinline__ void build_frags(const f32x16& t0, const f32x16& t1,
                                            int hi, hf8& F0, hf8& F1, hf8& F2) {
    const unsigned w0 = pk2_relu(t0[0],  t0[1]);
    const unsigned w1 = pk2_relu(t0[2],  t0[3]);
    const unsigned w2 = pk2_relu(t0[4],  t0[5]);
    const unsigned w3 = pk2_relu(t0[6],  t0[7]);
    const unsigned w4 = pk2_relu(t0[8],  t0[9]);
    const unsigned w5 = pk2_relu(t0[10], t0[11]);
    const unsigned w6 = pk2_relu(t0[12], t0[13]);
    const unsigned w7 = pk2_relu(t0[14], t0[15]);
    const unsigned w8 = pk2_relu(t1[0],  t1[1]);
    const unsigned w9 = pk2_relu(t1[2],  t1[3]);
    const unsigned p0 = pswap(w0), p1 = pswap(w1), p2 = pswap(w2), p3 = pswap(w3);
    const unsigned p4 = pswap(w4), p5 = pswap(w5), p6 = pswap(w6), p7 = pswap(w7);
    const unsigned p8 = pswap(w8), p9 = pswap(w9);
    F0 = frag_from(hi ? p2 : w0, hi ? p3 : w1, hi ? w2 : p0, hi ? w3 : p1);
    F1 = frag_from(hi ? p6 : w4, hi ? p7 : w5, hi ? w6 : p4, hi ? w7 : p5);
    F2 = frag_from(hi ? 0x00003c00u : w8, hi ? 0u : w9, hi ? 0u : p8, hi ? 0u : p9);
}

// hidden-layer A fragment (IN=40 + bias at k=40)
template<int IN, int OUT>
__device__ hf8 load_wfrag(const float* __restrict__ w, const float* __restrict__ b,
                          int mt, int ks, int lane) {
    const int r = mt * 32 + (lane & 31);
    const int kbase = ks * 16 + ((lane >> 5) & 1) * 8;
    hf8 f;
#pragma unroll
    for (int j = 0; j < 8; ++j) {
        const int k = kbase + j;
        float v = 0.f;
        if (r < OUT) {
            if (k < IN) v = w[r * IN + k];
            else if (k == IN) v = b[r];
        }
        f[j] = (__fp16)v;
    }
    return f;
}

// layer-1 A fragment, padded K map (IN fixed at 10)
template<int OUT>
__device__ hf8 load_wfrag_l1(const float* __restrict__ w, const float* __restrict__ b,
                             int mt, int lane) {
    const int r = mt * 32 + (lane & 31);
    const int kbase = ((lane >> 5) & 1) * 8;
    hf8 f;
#pragma unroll
    for (int j = 0; j < 8; ++j) {
        const int k = kbase + j;
        float v = 0.f;
        if (r < OUT) {
            int src = -1;
            if (k < 3) src = k;                       // xd
            else if (k >= 4 && k < 7) src = k - 1;    // xs
            else if (k >= 8 && k < 12) src = k - 2;   // ea/msg
            if (src >= 0) v = w[r * 10 + src];
            else if (k == 12) v = b[r];
        }
        f[j] = (__fp16)v;
    }
    return f;
}

template<bool IS_MSG>
__global__ __launch_bounds__(256, 2) void edge_kernel(
    const uint2* __restrict__ nodef,  // packed f16x4 node feats (msg: x; out: xt)
    const int*   __restrict__ ei,
    const void*  __restrict__ eattr,  // msg: ea f32[E,4];  out: emsg uint2[E]
    const float* __restrict__ w1, const float* __restrict__ b1,
    const float* __restrict__ w2, const float* __restrict__ b2,
    const float* __restrict__ w3, const float* __restrict__ b3,
    uint2* __restrict__ emsg_out,     // msg only
    float* __restrict__ out,          // out only
    int n_edges)
{
    const int lane = threadIdx.x & 63;
    const int ecol = lane & 31;
    const int hi = lane >> 5;

    hf8 wa1[2], wa2[2][3], wa3[3];
#pragma unroll
    for (int t = 0; t < 2; ++t) wa1[t] = load_wfrag_l1<40>(w1, b1, t, lane);
#pragma unroll
    for (int t = 0; t < 2; ++t)
#pragma unroll
        for (int s = 0; s < 3; ++s) wa2[t][s] = load_wfrag<40, 40>(w2, b2, t, s, lane);
#pragma unroll
    for (int s = 0; s < 3; ++s)
        wa3[s] = load_wfrag<40, (IS_MSG ? 4 : 1)>(w3, b3, 0, s, lane);

    const int gwave = (int)((blockIdx.x * blockDim.x + threadIdx.x) >> 6);
    const int nwave = (int)((gridDim.x * blockDim.x) >> 6);
    const int nchunk = (n_edges + NEPC - 1) / NEPC;
    const int last = n_edges - 1;

    int c = gwave;
    if (c >= nchunk) return;
    auto eclampX = [&](int cc) { int e = cc * NEPC + ecol;      return e < last ? e : last; };
    auto eclampY = [&](int cc) { int e = cc * NEPC + 32 + ecol; return e < last ? e : last; };

    // ---- prologue: stage features for chunk c; prefetch indices for c+nwave ----
    uint2 fAX, fBX, fAY, fBY;
    int sNX = 0, dNX = 0, sNY = 0, dNY = 0;
    {
        const int eX = eclampX(c), eY = eclampY(c);
        if (hi == 0) {
            const int sX = ei[eX], dX = ei[n_edges + eX];
            const int sY = ei[eY], dY = ei[n_edges + eY];
            fAX = nodef[dX]; fBX = nodef[sX];
            fAY = nodef[dY]; fBY = nodef[sY];
            const int e2X = eclampX(c + nwave), e2Y = eclampY(c + nwave);
            sNX = ei[e2X]; dNX = ei[n_edges + e2X];
            sNY = ei[e2Y]; dNY = ei[n_edges + e2Y];
        } else {
            if (IS_MSG) {
                const float4 evX = ((const float4*)eattr)[eX];
                fAX = make_uint2(pk2(evX.x, evX.y), pk2(evX.z, evX.w));
                const float4 evY = ((const float4*)eattr)[eY];
                fAY = make_uint2(pk2(evY.x, evY.y), pk2(evY.z, evY.w));
            } else {
                fAX = ((const uint2*)eattr)[eX];
                fAY = ((const uint2*)eattr)[eY];
            }
            fBX = make_uint2(0x00003c00u, 0u);   // bias word {1.0h, 0h}
            fBY = fBX;
        }
    }

    for (; c < nchunk; ) {
        const int cn = c + nwave;

        // layer-1 B fragments from staged registers
        const hf8 bfX = frag_from(fAX.x, fAX.y, fBX.x, fBX.y);
        const hf8 bfY = frag_from(fAY.x, fAY.y, fBY.x, fBY.y);

        // prefetch next chunk (features via last iter's indices; indices for cn+nwave)
        uint2 nfAX = fAX, nfBX = fBX, nfAY = fAY, nfBY = fBY;
        int sPX = sNX, dPX = dNX, sPY = sNY, dPY = dNY;
        {
            if (hi == 0) {
                nfAX = nodef[dNX]; nfBX = nodef[sNX];
                nfAY = nodef[dNY]; nfBY = nodef[sNY];
                const int e3X = eclampX(cn + nwave), e3Y = eclampY(cn + nwave);
                sPX = ei[e3X]; dPX = ei[n_edges + e3X];
                sPY = ei[e3Y]; dPY = ei[n_edges + e3Y];
            } else {
                const int e2X = eclampX(cn), e2Y = eclampY(cn);
                if (IS_MSG) {
                    const float4 evX = ((const float4*)eattr)[e2X];
                    nfAX = make_uint2(pk2(evX.x, evX.y), pk2(evX.z, evX.w));
                    const float4 evY = ((const float4*)eattr)[e2Y];
                    nfAY = make_uint2(pk2(evY.x, evY.y), pk2(evY.z, evY.w));
                } else {
                    nfAX = ((const uint2*)eattr)[e2X];
                    nfAY = ((const uint2*)eattr)[e2Y];
                }
            }
        }

        // layer 1 (K=16 padded input) — both tiles
        f32x16 a0X = {}, a1X = {}, a0Y = {}, a1Y = {};
        a0X = mfma16(wa1[0], bfX, a0X);
        a0Y = mfma16(wa1[0], bfY, a0Y);
        a1X = mfma16(wa1[1], bfX, a1X);
        a1Y = mfma16(wa1[1], bfY, a1Y);

        // transition 1 — both tiles (VALU/DS of one overlaps MFMA of the other)
        hf8 f0X, f1X, f2X, f0Y, f1Y, f2Y;
        build_frags(a0X, a1X, hi, f0X, f1X, f2X);
        build_frags(a0Y, a1Y, hi, f0Y, f1Y, f2Y);

        // layer 2 (K=48) — interleaved
        f32x16 c0X = {}, c1X = {}, c0Y = {}, c1Y = {};
        c0X = mfma16(wa2[0][0], f0X, c0X); c0Y = mfma16(wa2[0][0], f0Y, c0Y);
        c1X = mfma16(wa2[1][0], f0X, c1X); c1Y = mfma16(wa2[1][0], f0Y, c1Y);
        c0X = mfma16(wa2[0][1], f1X, c0X); c0Y = mfma16(wa2[0][1], f1Y, c0Y);
        c1X = mfma16(wa2[1][1], f1X, c1X); c1Y = mfma16(wa2[1][1], f1Y, c1Y);
        c0X = mfma16(wa2[0][2], f2X, c0X); c0Y = mfma16(wa2[0][2], f2Y, c0Y);
        c1X = mfma16(wa2[1][2], f2X, c1X); c1Y = mfma16(wa2[1][2], f2Y, c1Y);

        // transition 2 — both tiles
        hf8 g0X, g1X, g2X, g0Y, g1Y, g2Y;
        build_frags(c0X, c1X, hi, g0X, g1X, g2X);
        build_frags(c0Y, c1Y, hi, g0Y, g1Y, g2Y);

        // layer 3 (K=48) — interleaved
        f32x16 z0X = {}, z0Y = {};
        z0X = mfma16(wa3[0], g0X, z0X); z0Y = mfma16(wa3[0], g0Y, z0Y);
        z0X = mfma16(wa3[1], g1X, z0X); z0Y = mfma16(wa3[1], g1Y, z0Y);
        z0X = mfma16(wa3[2], g2X, z0X); z0Y = mfma16(wa3[2], g2Y, z0Y);

        // heads: lanes 0..31 hold channels 0..3 of their edge in regs 0..3
        if (hi == 0) {
            const int eX = c * NEPC + ecol;
            const int eY = eX + 32;
            if (eX < n_edges) {
                if (IS_MSG)
                    emsg_out[eX] = make_uint2(pk2(z0X[0], z0X[1]), pk2(z0X[2], z0X[3]));
                else
                    out[eX] = 1.f / (1.f + expf(-z0X[0]));
            }
            if (eY < n_edges) {
                if (IS_MSG)
                    emsg_out[eY] = make_uint2(pk2(z0Y[0], z0Y[1]), pk2(z0Y[2], z0Y[3]));
                else
                    out[eY] = 1.f / (1.f + expf(-z0Y[0]));
            }
        }

        // rotate pipeline registers
        fAX = nfAX; fBX = nfBX; fAY = nfAY; fBY = nfBY;
        sNX = sPX; dNX = dPX; sNY = sPY; dNY = dPY;
        c = cn;
    }
}

// ---- node feature packing: x f32[N,3] -> uint2 {pk(x0,x1), pk(x2,0)} ----
__global__ __launch_bounds__(256) void nodef_kernel(
    const float* __restrict__ x, uint2* __restrict__ nodef, int n_nodes)
{
    int n = blockIdx.x * blockDim.x + threadIdx.x;
    if (n >= n_nodes) return;
    nodef[n] = make_uint2(pk2(x[n * 3 + 0], x[n * 3 + 1]), pk2(x[n * 3 + 2], 0.f));
}

// ---- aggregation phase 1: per-(bin, edge-chunk) LDS accumulation ----
__device__ __forceinline__ void bin_accum(float* __restrict__ bin, int bbase, int d,
                                          const uint2* __restrict__ emsg, long long e) {
    const unsigned nl = (unsigned)(d - bbase);
    if (nl < (unsigned)BS) {
        const uint2 mv = emsg[e];
        f16x2 lo = __builtin_bit_cast(f16x2, mv.x);
        f16x2 hi = __builtin_bit_cast(f16x2, mv.y);
        float* p = bin + nl * 4;
        atomicAdd(p + 0, (float)lo.x);
        atomicAdd(p + 1, (float)lo.y);
        atomicAdd(p + 2, (float)hi.x);
        atomicAdd(p + 3, (float)hi.y);
    }
}

__global__ __launch_bounds__(1024) void bin_kernel(
    const int* __restrict__ ei,
    const uint2* __restrict__ emsg,
    float* __restrict__ scratch,      // [B*nw][BS*4]
    int n_edges, int nw)
{
    __shared__ float bin[BS * 4];     // 64 KB
    const int B = gridDim.x / nw;
    const int wchunk = blockIdx.x / B;
    const int b = blockIdx.x % B;
    const int bbase = b * BS;
    const int tid = threadIdx.x;

#pragma unroll
    for (int i = 0; i < (BS * 4) / 1024; ++i)
        bin[tid + i * 1024] = 0.f;
    __syncthreads();

    long long e0 = ((long long)n_edges * wchunk / nw) & ~3LL;
    long long e1 = (wchunk == nw - 1) ? (long long)n_edges
                                      : (((long long)n_edges * (wchunk + 1) / nw) & ~3LL);
    const long long nfull = (e1 - e0) >> 2;            // int4 groups
    const int* dstp = ei + n_edges;

    // 4 int4 groups (16 edges) per thread-iteration: 4 independent loads in flight
    for (long long base = 0; base < nfull; base += 4096) {
        int4 d4[4];
        long long t0 = base + tid;
#pragma unroll
        for (int k = 0; k < 4; ++k) {
            const long long t = t0 + k * 1024;
            if (t < nfull) d4[k] = *(const int4*)(dstp + e0 + t * 4);
        }
#pragma unroll
        for (int k = 0; k < 4; ++k) {
            const long long t = t0 + k * 1024;
            if (t < nfull) {
                const long long e = e0 + t * 4;
                bin_accum(bin, bbase, d4[k].x, emsg, e + 0);
                bin_accum(bin, bbase, d4[k].y, emsg, e + 1);
                bin_accum(bin, bbase, d4[k].z, emsg, e + 2);
                bin_accum(bin, bbase, d4[k].w, emsg, e + 3);
            }
        }
    }
    // tail (0..3 edges)
    for (long long e = e0 + nfull * 4 + tid; e < e1; e += 1024)
        bin_accum(bin, bbase, dstp[e], emsg, e);

    __syncthreads();

    float4* dst = (float4*)(scratch + ((size_t)(b * nw + wchunk)) * BS * 4);
    const float4* srcb = (const float4*)bin;
#pragma unroll
    for (int i = 0; i < (BS * 4) / 4 / 1024; ++i)
        dst[tid + i * 1024] = srcb[tid + i * 1024];
}

// ---- aggregation phase 2: sum chunk partials -> aggr f32[N][4] ----
__global__ __launch_bounds__(256) void reduce_kernel(
    const float* __restrict__ scratch,
    float* __restrict__ aggr,
    int n_nodes, int nw)
{
    int n = blockIdx.x * blockDim.x + threadIdx.x;
    if (n >= n_nodes) return;
    const int b = n / BS, nl = n % BS;
    float4 acc = make_float4(0.f, 0.f, 0.f, 0.f);
    for (int w = 0; w < nw; ++w) {
        const float4 v = *(const float4*)(scratch + ((size_t)(b * nw + w) * BS + nl) * 4);
        acc.x += v.x; acc.y += v.y; acc.z += v.z; acc.w += v.w;
    }
    *(float4*)(aggr + (size_t)n * 4) = acc;
}

template<int IN, int OUT, bool RELU>
__device__ __forceinline__ void dense(const float* __restrict__ w,
                                      const float* __restrict__ b,
                                      const float* in, float* out) {
#pragma unroll
    for (int j = 0; j < OUT; ++j) {
        float acc = b[j];
#pragma unroll
        for (int k = 0; k < IN; ++k) acc = fmaf(w[j * IN + k], in[k], acc);
        out[j] = RELU ? fmaxf(acc, 0.f) : acc;
    }
}

__global__ __launch_bounds__(256) void node_kernel(
    const float* __restrict__ x,
    const float* __restrict__ aggr,
    const float* __restrict__ w1, const float* __restrict__ b1,
    const float* __restrict__ w2, const float* __restrict__ b2,
    const float* __restrict__ w3, const float* __restrict__ b3,
    uint2* __restrict__ xth,          // packed f16x4 output
    int n_nodes)
{
    int n = blockIdx.x * blockDim.x + threadIdx.x;
    if (n >= n_nodes) return;

    float in[7];
    in[0] = x[n * 3 + 0]; in[1] = x[n * 3 + 1]; in[2] = x[n * 3 + 2];
    const float4 ag = *(const float4*)(aggr + (size_t)n * 4);
    in[3] = ag.x; in[4] = ag.y; in[5] = ag.z; in[6] = ag.w;

    float h1[40], h2[40], o[3];
    dense<7, 40, true >(w1, b1, in, h1);
    dense<40, 40, true>(w2, b2, h1, h2);
    dense<40, 3, false>(w3, b3, h2, o);

    xth[n] = make_uint2(pk2(o[0], o[1]), pk2(o[2], 0.f));
}

extern "C" void kernel_launch(void* const* d_in, const int* in_sizes, int n_in,
                              void* d_out, int out_size, void* d_ws, size_t ws_size,
                              hipStream_t stream) {
    const float* x  = (const float*)d_in[0];
    const int*   ei = (const int*)d_in[1];   // int64 delivered as int32
    const float* ea = (const float*)d_in[2];

    const float* r1_w1 = (const float*)d_in[3];
    const float* r1_b1 = (const float*)d_in[4];
    const float* r1_w2 = (const float*)d_in[5];
    const float* r1_b2 = (const float*)d_in[6];
    const float* r1_w3 = (const float*)d_in[7];
    const float* r1_b3 = (const float*)d_in[8];

    const float* o_w1 = (const float*)d_in[9];
    const float* o_b1 = (const float*)d_in[10];
    const float* o_w2 = (const float*)d_in[11];
    const float* o_b2 = (const float*)d_in[12];
    const float* o_w3 = (const float*)d_in[13];
    const float* o_b3 = (const float*)d_in[14];

    const float* r2_w1 = (const float*)d_in[15];
    const float* r2_b1 = (const float*)d_in[16];
    const float* r2_w2 = (const float*)d_in[17];
    const float* r2_b2 = (const float*)d_in[18];
    const float* r2_w3 = (const float*)d_in[19];
    const float* r2_b3 = (const float*)d_in[20];

    const int n_nodes = in_sizes[0] / 3;
    const int n_edges = in_sizes[2] / 4;
    const int B = (n_nodes + BS - 1) / BS;

    // ws: nodef uint2[N] | aggr f32[N*4] | emsg uint2[E] | scratch f32[B*nw*BS*4]
    uint2* nodef   = (uint2*)d_ws;
    float* aggr    = (float*)(nodef + n_nodes);
    uint2* emsg    = (uint2*)(aggr + (size_t)n_nodes * 4);
    float* scratch = (float*)(emsg + n_edges);

    const size_t fixed_bytes = (size_t)n_nodes * 8 + (size_t)n_nodes * 16
                             + (size_t)n_edges * 8;
    int nw = 32;
    while (nw > 8 && ws_size < fixed_bytes + (size_t)B * nw * BS * 4 * sizeof(float))
        nw >>= 1;

    const int eb = 1024;                // offer 4 blocks/CU (residency = f(VGPR))
    const int nb = (n_nodes + 255) / 256;

    nodef_kernel<<<nb, 256, 0, stream>>>(x, nodef, n_nodes);

    edge_kernel<true><<<eb, 256, 0, stream>>>(nodef, ei, (const void*)ea,
        r1_w1, r1_b1, r1_w2, r1_b2, r1_w3, r1_b3,
        emsg, nullptr, n_edges);

    bin_kernel<<<B * nw, 1024, 0, stream>>>(ei, emsg, scratch, n_edges, nw);

    reduce_kernel<<<nb, 256, 0, stream>>>(scratch, aggr, n_nodes, nw);

    node_kernel<<<nb, 256, 0, stream>>>(x, aggr,
        o_w1, o_b1, o_w2, o_b2, o_w3, o_b3, nodef, n_nodes);

    edge_kernel<false><<<eb, 256, 0, stream>>>(nodef, ei, (const void*)emsg,
        r2_w1, r2_b1, r2_w2, r2_b2, r2_w3, r2_b3,
        nullptr, (float*)d_out, n_edges);
}